// Round 2
// baseline (614.517 us; speedup 1.0000x reference)
//
#include <hip/hip_runtime.h>
#include <hip/hip_bf16.h>

#define DIM 64
#define SCALE 0.125f

// ---------------- CSR build ----------------

__global__ void k_hist(const int* __restrict__ recv, int* __restrict__ deg, int E) {
    int e = blockIdx.x * blockDim.x + threadIdx.x;
    if (e < E) atomicAdd(&deg[recv[e]], 1);
}

__global__ __launch_bounds__(1024) void k_scan1(const int* __restrict__ deg,
                                                int* __restrict__ incl,
                                                int* __restrict__ bsums, int N) {
    __shared__ int sm[1024];
    int t = threadIdx.x;
    int i = blockIdx.x * 1024 + t;
    int v = (i < N) ? deg[i] : 0;
    sm[t] = v;
    __syncthreads();
    for (int off = 1; off < 1024; off <<= 1) {
        int add = (t >= off) ? sm[t - off] : 0;
        __syncthreads();
        sm[t] += add;
        __syncthreads();
    }
    if (i < N) incl[i] = sm[t];
    if (t == 1023) bsums[blockIdx.x] = sm[1023];
}

__global__ void k_scan2(int* __restrict__ bsums, int NB) {
    if (threadIdx.x == 0 && blockIdx.x == 0) {
        int ex = 0;
        for (int b = 0; b < NB; b++) { int t = bsums[b]; bsums[b] = ex; ex += t; }
    }
}

__global__ void k_scan3(const int* __restrict__ deg, const int* __restrict__ bsums,
                        int* __restrict__ offs, int* __restrict__ cursor, int N, int E) {
    int i = blockIdx.x * blockDim.x + threadIdx.x;
    if (i < N) {
        int ex = offs[i] - deg[i] + bsums[i >> 10];
        offs[i] = ex;
        cursor[i] = ex;
    }
    if (i == 0) offs[N] = E;
}

__global__ void k_scatter(const int* __restrict__ send, const int* __restrict__ recv,
                          int* __restrict__ cursor, int* __restrict__ csr, int E) {
    int e = blockIdx.x * blockDim.x + threadIdx.x;
    if (e < E) {
        int pos = atomicAdd(&cursor[recv[e]], 1);
        csr[pos] = send[e];
    }
}

// ---------------- fused QKV GEMM ----------------
// Row-per-lane layout: block = 192 threads (3 waves; wave m handles W_m) over a
// 64-row x-chunk. x staged TRANSPOSED in LDS (xs[k][row], row stride 68 floats
// -> the per-k read xs[k*68+lane] is lane-consecutive = conflict-free).
// Inner loop per k: 1 ds_read_b32 + 16 wave-uniform L1-hit float4 W loads
// + 64 FMAs into acc[64] VGPRs. LDS traffic: 1 b32 per 64 FMAs (the R1 version
// paid 1 b128 per 4 FMAs and saturated the per-CU LDS return path).
__global__ __launch_bounds__(192) void k_qkv(const float* __restrict__ x,
                                             const float* __restrict__ Wq,
                                             const float* __restrict__ Wk,
                                             const float* __restrict__ Wv,
                                             float* __restrict__ Q,
                                             float* __restrict__ KV, int N) {
    __shared__ float xs[64 * 68];  // [k][row], row-stride 68 floats (pad)
    int tid = threadIdx.x;
    int wv = tid >> 6;     // matrix id: 0=Q 1=K 2=V
    int lane = tid & 63;   // row within chunk
    int base = blockIdx.x * 64;

    // stage transposed: x[base+row][c] -> xs[c*68 + row]
    for (int f = tid; f < 1024; f += 192) {
        int row = f >> 4, c4 = f & 15;
        float4 val = make_float4(0.f, 0.f, 0.f, 0.f);
        if (base + row < N) val = ((const float4*)x)[(base + row) * 16 + c4];
        xs[(c4 * 4 + 0) * 68 + row] = val.x;
        xs[(c4 * 4 + 1) * 68 + row] = val.y;
        xs[(c4 * 4 + 2) * 68 + row] = val.z;
        xs[(c4 * 4 + 3) * 68 + row] = val.w;
    }
    __syncthreads();

    const float* W = (wv == 0) ? Wq : ((wv == 1) ? Wk : Wv);
    int row = base + lane;

    float acc[64];
#pragma unroll
    for (int j = 0; j < 64; j++) acc[j] = 0.f;

    const float* xcol = xs + lane;
#pragma unroll 2
    for (int k = 0; k < 64; k++) {
        float xv = xcol[k * 68];
        const float4* Wr = (const float4*)&W[k * 64];
#pragma unroll
        for (int j4 = 0; j4 < 16; j4++) {
            float4 w = Wr[j4];
            acc[j4 * 4 + 0] = fmaf(xv, w.x, acc[j4 * 4 + 0]);
            acc[j4 * 4 + 1] = fmaf(xv, w.y, acc[j4 * 4 + 1]);
            acc[j4 * 4 + 2] = fmaf(xv, w.z, acc[j4 * 4 + 2]);
            acc[j4 * 4 + 3] = fmaf(xv, w.w, acc[j4 * 4 + 3]);
        }
    }

    if (row < N) {
        float* dst = (wv == 0) ? &Q[row * 64] : &KV[row * 128 + (wv - 1) * 64];
#pragma unroll
        for (int j4 = 0; j4 < 16; j4++)
            ((float4*)dst)[j4] = make_float4(acc[4 * j4], acc[4 * j4 + 1],
                                             acc[4 * j4 + 2], acc[4 * j4 + 3]);
    }
}

// ---------------- attention + fused output GEMM ----------------
// One wave per receiver node; lane = (group g = lane>>4, sublane). Each group
// handles one edge, sublane covers 4 dims -> 4 edges per wave-iteration.
// 1-deep software prefetch of next batch (csr + K + V) so a gather round is in
// flight during the shfl-reduce. Wo lives in a per-block LDS copy (frees 64
// VGPRs vs the register version -> ~2x occupancy on this latency-bound kernel);
// epilogue Wo reads are lane-consecutive ds_read_b32 (conflict-free), amortized
// once per node.
__global__ __launch_bounds__(256) void k_attn(const float* __restrict__ Q,
                                              const float* __restrict__ KV,
                                              const float* __restrict__ x,
                                              const float* __restrict__ Wo,
                                              const int* __restrict__ offs,
                                              const int* __restrict__ csr,
                                              float* __restrict__ out, int N) {
    __shared__ float wos[64 * 64];          // Wo[k][j] at wos[k*64+j]
    __shared__ __align__(16) float osh[4][64];
    int tid = threadIdx.x;
    int wv = tid >> 6;
    int lane = tid & 63;
    int g = lane >> 4;
    int sub = lane & 15;

    for (int i = tid; i < 4096; i += 256) wos[i] = Wo[i];
    __syncthreads();

    const float4* KV4 = (const float4*)KV;
    const float4* Q4 = (const float4*)Q;

    int wave_id = blockIdx.x * 4 + wv;
    int nwaves = gridDim.x * 4;

    for (int r = wave_id; r < N; r += nwaves) {
        int start = offs[r];
        int end = offs[r + 1];
        float4 q4 = Q4[r * 16 + sub];
        float4 acc = make_float4(0.f, 0.f, 0.f, 0.f);
        float dpart = 0.f;

        // prologue: batch 0 in flight
        int e0 = start + g;
        bool valid = e0 < end;
        int s = valid ? csr[e0] : 0;
        float4 k4 = KV4[s * 32 + sub];
        float4 v4 = KV4[s * 32 + 16 + sub];

        for (int b = start; b < end; b += 4) {
            // prefetch next batch
            int en = b + 4 + g;
            bool vn = en < end;
            int sn = vn ? csr[en] : 0;
            float4 k4n = KV4[sn * 32 + sub];
            float4 v4n = KV4[sn * 32 + 16 + sub];

            // process current batch
            float dot = q4.x * k4.x + q4.y * k4.y + q4.z * k4.z + q4.w * k4.w;
            dot += __shfl_xor(dot, 1);
            dot += __shfl_xor(dot, 2);
            dot += __shfl_xor(dot, 4);
            dot += __shfl_xor(dot, 8);
            float w = valid ? __expf(dot * SCALE) : 0.f;
            acc.x = fmaf(w, v4.x, acc.x);
            acc.y = fmaf(w, v4.y, acc.y);
            acc.z = fmaf(w, v4.z, acc.z);
            acc.w = fmaf(w, v4.w, acc.w);
            dpart += w;

            k4 = k4n; v4 = v4n; valid = vn;
        }

        // combine the 4 groups' partials
        dpart += __shfl_xor(dpart, 16); dpart += __shfl_xor(dpart, 32);
        acc.x += __shfl_xor(acc.x, 16); acc.x += __shfl_xor(acc.x, 32);
        acc.y += __shfl_xor(acc.y, 16); acc.y += __shfl_xor(acc.y, 32);
        acc.z += __shfl_xor(acc.z, 16); acc.z += __shfl_xor(acc.z, 32);
        acc.w += __shfl_xor(acc.w, 16); acc.w += __shfl_xor(acc.w, 32);

        float inv = (dpart > 0.f) ? (1.0f / dpart) : 0.f;
        float4 o4 = make_float4(acc.x * inv, acc.y * inv, acc.z * inv, acc.w * inv);

        if (g == 0) *((float4*)&osh[wv][sub * 4]) = o4;
        asm volatile("s_waitcnt lgkmcnt(0)" ::: "memory");

        float res = x[r * 64 + lane];
        const float4* o4p = (const float4*)&osh[wv][0];
#pragma unroll
        for (int k4i = 0; k4i < 16; k4i++) {
            float4 ov = o4p[k4i];
            res = fmaf(ov.x, wos[(k4i * 4 + 0) * 64 + lane], res);
            res = fmaf(ov.y, wos[(k4i * 4 + 1) * 64 + lane], res);
            res = fmaf(ov.z, wos[(k4i * 4 + 2) * 64 + lane], res);
            res = fmaf(ov.w, wos[(k4i * 4 + 3) * 64 + lane], res);
        }
        out[r * 64 + lane] = res;
        asm volatile("s_waitcnt lgkmcnt(0)" ::: "memory");  // osh reads done before next node
    }
}

// ---------------- launch ----------------

extern "C" void kernel_launch(void* const* d_in, const int* in_sizes, int n_in,
                              void* d_out, int out_size, void* d_ws, size_t ws_size,
                              hipStream_t stream) {
    const float* x  = (const float*)d_in[0];
    const int* edge = (const int*)d_in[1];
    const float* Wq = (const float*)d_in[2];
    const float* Wk = (const float*)d_in[3];
    const float* Wv = (const float*)d_in[4];
    const float* Wo = (const float*)d_in[5];
    float* out = (float*)d_out;

    int N = in_sizes[0] / DIM;
    int E = in_sizes[1] / 2;

    char* p = (char*)d_ws;
    auto carve = [&](size_t bytes) {
        char* r = p;
        p += ((bytes + 255) / 256) * 256;
        return r;
    };
    float* Q      = (float*)carve((size_t)N * 64 * 4);
    float* KV     = (float*)carve((size_t)N * 128 * 4);
    int*   deg    = (int*)carve((size_t)N * 4);
    int*   offs   = (int*)carve((size_t)(N + 1) * 4);
    int*   cursor = (int*)carve((size_t)N * 4);
    int*   bsums  = (int*)carve(4096);
    int*   csr    = (int*)carve((size_t)E * 4);
    (void)ws_size; (void)n_in; (void)out_size;

    const int* send = edge;
    const int* recv = edge + E;

    hipMemsetAsync(deg, 0, (size_t)N * 4, stream);
    k_hist<<<(E + 255) / 256, 256, 0, stream>>>(recv, deg, E);
    int NB = (N + 1023) / 1024;
    k_scan1<<<NB, 1024, 0, stream>>>(deg, offs, bsums, N);
    k_scan2<<<1, 64, 0, stream>>>(bsums, NB);
    k_scan3<<<(N + 255) / 256, 256, 0, stream>>>(deg, bsums, offs, cursor, N, E);
    k_scatter<<<(E + 255) / 256, 256, 0, stream>>>(send, recv, cursor, csr, E);
    k_qkv<<<(N + 63) / 64, 192, 0, stream>>>(x, Wq, Wk, Wv, Q, KV, N);
    k_attn<<<2048, 256, 0, stream>>>(Q, KV, x, Wo, offs, csr, out, N);
}

// Round 3
// 457.807 us; speedup vs baseline: 1.3423x; 1.3423x over previous
//
#include <hip/hip_runtime.h>
#include <hip/hip_bf16.h>

#define DIM 64
#define SCALE 0.125f

// ---------------- CSR build ----------------

__global__ void k_hist(const int* __restrict__ recv, int* __restrict__ deg, int E) {
    int e = blockIdx.x * blockDim.x + threadIdx.x;
    if (e < E) atomicAdd(&deg[recv[e]], 1);
}

__global__ __launch_bounds__(1024) void k_scan1(const int* __restrict__ deg,
                                                int* __restrict__ incl,
                                                int* __restrict__ bsums, int N) {
    __shared__ int sm[1024];
    int t = threadIdx.x;
    int i = blockIdx.x * 1024 + t;
    int v = (i < N) ? deg[i] : 0;
    sm[t] = v;
    __syncthreads();
    for (int off = 1; off < 1024; off <<= 1) {
        int add = (t >= off) ? sm[t - off] : 0;
        __syncthreads();
        sm[t] += add;
        __syncthreads();
    }
    if (i < N) incl[i] = sm[t];
    if (t == 1023) bsums[blockIdx.x] = sm[1023];
}

__global__ void k_scan2(int* __restrict__ bsums, int NB) {
    if (threadIdx.x == 0 && blockIdx.x == 0) {
        int ex = 0;
        for (int b = 0; b < NB; b++) { int t = bsums[b]; bsums[b] = ex; ex += t; }
    }
}

__global__ void k_scan3(const int* __restrict__ deg, const int* __restrict__ bsums,
                        int* __restrict__ offs, int* __restrict__ cursor, int N, int E) {
    int i = blockIdx.x * blockDim.x + threadIdx.x;
    if (i < N) {
        int ex = offs[i] - deg[i] + bsums[i >> 10];
        offs[i] = ex;
        cursor[i] = ex;
    }
    if (i == 0) offs[N] = E;
}

__global__ void k_scatter(const int* __restrict__ send, const int* __restrict__ recv,
                          int* __restrict__ cursor, int* __restrict__ csr, int E) {
    int e = blockIdx.x * blockDim.x + threadIdx.x;
    if (e < E) {
        int pos = atomicAdd(&cursor[recv[e]], 1);
        csr[pos] = send[e];
    }
}

// ---------------- QKV GEMM: 8x8 register tiling ----------------
// One matrix per block (m = bid / nchunk); block = 4 waves, each wave owns a
// private 64-row x chunk staged TRANSPOSED in LDS (xs[k][row]). W staged once
// per block (16 KB). Per k-step per lane: 2 ds_read_b128 (8 x-rows) +
// 2 ds_read_b128 (8 W-cols) + 64 FMAs into an 8x8 register tile.
// 16 FMAs per b128 (vs 4 in R1) leaves LDS ~1.5x from bound instead of 6x.
// R2's failure (compiler scalarized wave-uniform W loads -> s_load K$ thrash,
// VALUBusy 7.8%) is avoided: both operands come through per-lane LDS reads.
__global__ __launch_bounds__(256) void k_qkv(const float* __restrict__ x,
                                             const float* __restrict__ Wq,
                                             const float* __restrict__ Wk,
                                             const float* __restrict__ Wv,
                                             float* __restrict__ Q,
                                             float* __restrict__ KV,
                                             int N, int nchunk) {
    __shared__ __align__(16) float ws[64 * 64];      // W[k][col]
    __shared__ __align__(16) float xs[4][64 * 64];   // per-wave: x^T[k][row]
    int tid = threadIdx.x;
    int wv = tid >> 6;
    int lane = tid & 63;
    int m = blockIdx.x / nchunk;       // 0=Q 1=K 2=V
    int cb = blockIdx.x % nchunk;
    const float* W = (m == 0) ? Wq : ((m == 1) ? Wk : Wv);

    // stage W cooperatively: 1024 float4, coalesced
    for (int i = tid; i < 1024; i += 256) ((float4*)ws)[i] = ((const float4*)W)[i];
    __syncthreads();

    int base = cb * 256 + wv * 64;
    if (base < N) {
        float* xw = xs[wv];
        // stage this wave's 64 rows transposed: lane = row
#pragma unroll
        for (int c4 = 0; c4 < 16; c4++) {
            float4 v = make_float4(0.f, 0.f, 0.f, 0.f);
            if (base + lane < N) v = ((const float4*)x)[(size_t)(base + lane) * 16 + c4];
            xw[(c4 * 4 + 0) * 64 + lane] = v.x;
            xw[(c4 * 4 + 1) * 64 + lane] = v.y;
            xw[(c4 * 4 + 2) * 64 + lane] = v.z;
            xw[(c4 * 4 + 3) * 64 + lane] = v.w;
        }
        asm volatile("s_waitcnt lgkmcnt(0)" ::: "memory");  // wave-private: no block sync needed

        int lr = lane >> 3;   // row group: rows 8*lr..+7 (8-way broadcast on x reads)
        int lc = lane & 7;    // col group: cols 8*lc..+7
        const float* xp = xw + lr * 8;
        const float* wp = ws + lc * 8;

        float acc[8][8];
#pragma unroll
        for (int i = 0; i < 8; i++)
#pragma unroll
            for (int j = 0; j < 8; j++) acc[i][j] = 0.f;

        float4 xa = *(const float4*)(xp);
        float4 xb = *(const float4*)(xp + 4);
        float4 wa = *(const float4*)(wp);
        float4 wb = *(const float4*)(wp + 4);
#pragma unroll 4
        for (int k = 0; k < 64; k++) {
            float4 xan, xbn, wan, wbn;
            if (k < 63) {
                xan = *(const float4*)(xp + (k + 1) * 64);
                xbn = *(const float4*)(xp + (k + 1) * 64 + 4);
                wan = *(const float4*)(wp + (k + 1) * 64);
                wbn = *(const float4*)(wp + (k + 1) * 64 + 4);
            }
            float xv[8] = {xa.x, xa.y, xa.z, xa.w, xb.x, xb.y, xb.z, xb.w};
            float wc[8] = {wa.x, wa.y, wa.z, wa.w, wb.x, wb.y, wb.z, wb.w};
#pragma unroll
            for (int i = 0; i < 8; i++)
#pragma unroll
                for (int j = 0; j < 8; j++)
                    acc[i][j] = fmaf(xv[i], wc[j], acc[i][j]);
            xa = xan; xb = xbn; wa = wan; wb = wbn;
        }

        // store: lane writes rows base+8lr..+7, cols 8lc..+7
#pragma unroll
        for (int i = 0; i < 8; i++) {
            int row = base + lr * 8 + i;
            if (row < N) {
                float* dst = (m == 0) ? &Q[(size_t)row * 64 + lc * 8]
                                      : &KV[(size_t)row * 128 + (m - 1) * 64 + lc * 8];
                ((float4*)dst)[0] = make_float4(acc[i][0], acc[i][1], acc[i][2], acc[i][3]);
                ((float4*)dst)[1] = make_float4(acc[i][4], acc[i][5], acc[i][6], acc[i][7]);
            }
        }
    }
}

// ---------------- attention + fused output GEMM ----------------
// One wave per receiver; lane = (group g = lane>>4, sublane). Group handles one
// edge, sublane covers 4 dims -> 4 edges/wave-iter. 2-deep software pipeline on
// (csr, K, V) gathers so a gather round is in flight across the shfl-reduce.
// Wo in LDS (frees 64 VGPRs); x[r] prefetched at loop head.
__global__ __launch_bounds__(256) void k_attn(const float* __restrict__ Q,
                                              const float* __restrict__ KV,
                                              const float* __restrict__ x,
                                              const float* __restrict__ Wo,
                                              const int* __restrict__ offs,
                                              const int* __restrict__ csr,
                                              float* __restrict__ out, int N) {
    __shared__ float wos[64 * 64];          // Wo[k][j] at wos[k*64+j]
    __shared__ __align__(16) float osh[4][64];
    int tid = threadIdx.x;
    int wv = tid >> 6;
    int lane = tid & 63;
    int g = lane >> 4;
    int sub = lane & 15;

    for (int i = tid; i < 4096; i += 256) wos[i] = Wo[i];
    __syncthreads();

    const float4* KV4 = (const float4*)KV;
    const float4* Q4 = (const float4*)Q;

    int wave_id = blockIdx.x * 4 + wv;
    int nwaves = gridDim.x * 4;

    for (int r = wave_id; r < N; r += nwaves) {
        int start = offs[r];
        int end = offs[r + 1];
        float xres = x[(size_t)r * 64 + lane];   // independent: issue early
        float4 q4 = Q4[r * 16 + sub];
        float4 acc = make_float4(0.f, 0.f, 0.f, 0.f);
        float dpart = 0.f;

        // 2-stage pipeline: A = batch b, B = batch b+4
        int eA = start + g;
        bool vA = eA < end;
        int sA = vA ? csr[eA] : 0;
        float4 kA = KV4[sA * 32 + sub];
        float4 uA = KV4[sA * 32 + 16 + sub];
        int eB = start + 4 + g;
        bool vB = eB < end;
        int sB = vB ? csr[eB] : 0;
        float4 kB = KV4[sB * 32 + sub];
        float4 uB = KV4[sB * 32 + 16 + sub];

        for (int b = start; b < end; b += 4) {
            // prefetch batch b+8 into stage C
            int eC = b + 8 + g;
            bool vC = eC < end;
            int sC = vC ? csr[eC] : 0;
            float4 kC = KV4[sC * 32 + sub];
            float4 uC = KV4[sC * 32 + 16 + sub];

            // process stage A
            float dot = q4.x * kA.x + q4.y * kA.y + q4.z * kA.z + q4.w * kA.w;
            dot += __shfl_xor(dot, 1);
            dot += __shfl_xor(dot, 2);
            dot += __shfl_xor(dot, 4);
            dot += __shfl_xor(dot, 8);
            float w = vA ? __expf(dot * SCALE) : 0.f;
            acc.x = fmaf(w, uA.x, acc.x);
            acc.y = fmaf(w, uA.y, acc.y);
            acc.z = fmaf(w, uA.z, acc.z);
            acc.w = fmaf(w, uA.w, acc.w);
            dpart += w;

            kA = kB; uA = uB; vA = vB;
            kB = kC; uB = uC; vB = vC;
        }

        // combine the 4 groups' partials
        dpart += __shfl_xor(dpart, 16); dpart += __shfl_xor(dpart, 32);
        acc.x += __shfl_xor(acc.x, 16); acc.x += __shfl_xor(acc.x, 32);
        acc.y += __shfl_xor(acc.y, 16); acc.y += __shfl_xor(acc.y, 32);
        acc.z += __shfl_xor(acc.z, 16); acc.z += __shfl_xor(acc.z, 32);
        acc.w += __shfl_xor(acc.w, 16); acc.w += __shfl_xor(acc.w, 32);

        float inv = (dpart > 0.f) ? (1.0f / dpart) : 0.f;
        float4 o4 = make_float4(acc.x * inv, acc.y * inv, acc.z * inv, acc.w * inv);

        if (g == 0) *((float4*)&osh[wv][sub * 4]) = o4;
        asm volatile("s_waitcnt lgkmcnt(0)" ::: "memory");

        float res = xres;
        const float4* o4p = (const float4*)&osh[wv][0];
#pragma unroll
        for (int k4i = 0; k4i < 16; k4i++) {
            float4 ov = o4p[k4i];
            res = fmaf(ov.x, wos[(k4i * 4 + 0) * 64 + lane], res);
            res = fmaf(ov.y, wos[(k4i * 4 + 1) * 64 + lane], res);
            res = fmaf(ov.z, wos[(k4i * 4 + 2) * 64 + lane], res);
            res = fmaf(ov.w, wos[(k4i * 4 + 3) * 64 + lane], res);
        }
        out[(size_t)r * 64 + lane] = res;
        asm volatile("s_waitcnt lgkmcnt(0)" ::: "memory");  // osh reads done before next node
    }
}

// ---------------- launch ----------------

extern "C" void kernel_launch(void* const* d_in, const int* in_sizes, int n_in,
                              void* d_out, int out_size, void* d_ws, size_t ws_size,
                              hipStream_t stream) {
    const float* x  = (const float*)d_in[0];
    const int* edge = (const int*)d_in[1];
    const float* Wq = (const float*)d_in[2];
    const float* Wk = (const float*)d_in[3];
    const float* Wv = (const float*)d_in[4];
    const float* Wo = (const float*)d_in[5];
    float* out = (float*)d_out;

    int N = in_sizes[0] / DIM;
    int E = in_sizes[1] / 2;

    char* p = (char*)d_ws;
    auto carve = [&](size_t bytes) {
        char* r = p;
        p += ((bytes + 255) / 256) * 256;
        return r;
    };
    float* Q      = (float*)carve((size_t)N * 64 * 4);
    float* KV     = (float*)carve((size_t)N * 128 * 4);
    int*   deg    = (int*)carve((size_t)N * 4);
    int*   offs   = (int*)carve((size_t)(N + 1) * 4);
    int*   cursor = (int*)carve((size_t)N * 4);
    int*   bsums  = (int*)carve(4096);
    int*   csr    = (int*)carve((size_t)E * 4);
    (void)ws_size; (void)n_in; (void)out_size;

    const int* send = edge;
    const int* recv = edge + E;

    hipMemsetAsync(deg, 0, (size_t)N * 4, stream);
    k_hist<<<(E + 255) / 256, 256, 0, stream>>>(recv, deg, E);
    int NB = (N + 1023) / 1024;
    k_scan1<<<NB, 1024, 0, stream>>>(deg, offs, bsums, N);
    k_scan2<<<1, 64, 0, stream>>>(bsums, NB);
    k_scan3<<<(N + 255) / 256, 256, 0, stream>>>(deg, bsums, offs, cursor, N, E);
    k_scatter<<<(E + 255) / 256, 256, 0, stream>>>(send, recv, cursor, csr, E);
    int nchunk = (N + 255) / 256;
    k_qkv<<<3 * nchunk, 256, 0, stream>>>(x, Wq, Wk, Wv, Q, KV, N, nchunk);
    k_attn<<<4096, 256, 0, stream>>>(Q, KV, x, Wo, offs, csr, out, N);
}

// Round 4
// 415.507 us; speedup vs baseline: 1.4790x; 1.1018x over previous
//
#include <hip/hip_runtime.h>
#include <hip/hip_bf16.h>

#define DIM 64
#define SCALE 0.125f

// ---------------- bf16 helpers (manual, RNE) ----------------
static __device__ __forceinline__ unsigned int pack2bf(float a, float b) {
    unsigned int ua = __float_as_uint(a), ub = __float_as_uint(b);
    ua += 0x7fffu + ((ua >> 16) & 1u);
    ub += 0x7fffu + ((ub >> 16) & 1u);
    return (ua >> 16) | (ub & 0xffff0000u);
}
static __device__ __forceinline__ float2 unpack2bf(unsigned int u) {
    return make_float2(__uint_as_float(u << 16), __uint_as_float(u & 0xffff0000u));
}

// ---------------- CSR build ----------------

__global__ void k_hist(const int* __restrict__ recv, int* __restrict__ deg, int E) {
    int e = blockIdx.x * blockDim.x + threadIdx.x;
    if (e < E) atomicAdd(&deg[recv[e]], 1);
}

__global__ __launch_bounds__(1024) void k_scan1(const int* __restrict__ deg,
                                                int* __restrict__ incl,
                                                int* __restrict__ bsums, int N) {
    __shared__ int sm[1024];
    int t = threadIdx.x;
    int i = blockIdx.x * 1024 + t;
    int v = (i < N) ? deg[i] : 0;
    sm[t] = v;
    __syncthreads();
    for (int off = 1; off < 1024; off <<= 1) {
        int add = (t >= off) ? sm[t - off] : 0;
        __syncthreads();
        sm[t] += add;
        __syncthreads();
    }
    if (i < N) incl[i] = sm[t];
    if (t == 1023) bsums[blockIdx.x] = sm[1023];
}

// parallel single-block scan over <=1024 block sums (R3's serial loop was ~98
// dependent L2 round-trips from one thread).
__global__ __launch_bounds__(1024) void k_scan2(int* __restrict__ bsums, int NB) {
    __shared__ int sm[1024];
    int t = threadIdx.x;
    int v = (t < NB) ? bsums[t] : 0;
    sm[t] = v;
    __syncthreads();
    for (int off = 1; off < 1024; off <<= 1) {
        int add = (t >= off) ? sm[t - off] : 0;
        __syncthreads();
        sm[t] += add;
        __syncthreads();
    }
    if (t < NB) bsums[t] = sm[t] - v;  // exclusive
}

__global__ void k_scan3(const int* __restrict__ deg, const int* __restrict__ bsums,
                        int* __restrict__ offs, int* __restrict__ cursor, int N, int E) {
    int i = blockIdx.x * blockDim.x + threadIdx.x;
    if (i < N) {
        int ex = offs[i] - deg[i] + bsums[i >> 10];
        offs[i] = ex;
        cursor[i] = ex;
    }
    if (i == 0) offs[N] = E;
}

__global__ void k_scatter(const int* __restrict__ send, const int* __restrict__ recv,
                          int* __restrict__ cursor, int* __restrict__ csr, int E) {
    int e = blockIdx.x * blockDim.x + threadIdx.x;
    if (e < E) {
        int pos = atomicAdd(&cursor[recv[e]], 1);
        csr[pos] = send[e];
    }
}

// ---------------- QKV GEMM: 8x8 register tiling ----------------
// Same structure as R3 (VALU-fed from per-lane LDS b128 reads, 16 FMA/b128).
// K,V now packed to bf16 (RNE) on store: halves KV write traffic and, more
// importantly, halves k_attn's gather bytes.
__global__ __launch_bounds__(256) void k_qkv(const float* __restrict__ x,
                                             const float* __restrict__ Wq,
                                             const float* __restrict__ Wk,
                                             const float* __restrict__ Wv,
                                             float* __restrict__ Q,
                                             unsigned int* __restrict__ KVb,  // bf16x2
                                             int N, int nchunk) {
    __shared__ __align__(16) float ws[64 * 64];      // W[k][col]
    __shared__ __align__(16) float xs[4][64 * 64];   // per-wave: x^T[k][row]
    int tid = threadIdx.x;
    int wv = tid >> 6;
    int lane = tid & 63;
    int m = blockIdx.x / nchunk;       // 0=Q 1=K 2=V
    int cb = blockIdx.x % nchunk;
    const float* W = (m == 0) ? Wq : ((m == 1) ? Wk : Wv);

    for (int i = tid; i < 1024; i += 256) ((float4*)ws)[i] = ((const float4*)W)[i];
    __syncthreads();

    int base = cb * 256 + wv * 64;
    if (base < N) {
        float* xw = xs[wv];
#pragma unroll
        for (int c4 = 0; c4 < 16; c4++) {
            float4 v = make_float4(0.f, 0.f, 0.f, 0.f);
            if (base + lane < N) v = ((const float4*)x)[(size_t)(base + lane) * 16 + c4];
            xw[(c4 * 4 + 0) * 64 + lane] = v.x;
            xw[(c4 * 4 + 1) * 64 + lane] = v.y;
            xw[(c4 * 4 + 2) * 64 + lane] = v.z;
            xw[(c4 * 4 + 3) * 64 + lane] = v.w;
        }
        asm volatile("s_waitcnt lgkmcnt(0)" ::: "memory");  // wave-private staging

        int lr = lane >> 3;
        int lc = lane & 7;
        const float* xp = xw + lr * 8;
        const float* wp = ws + lc * 8;

        float acc[8][8];
#pragma unroll
        for (int i = 0; i < 8; i++)
#pragma unroll
            for (int j = 0; j < 8; j++) acc[i][j] = 0.f;

        float4 xa = *(const float4*)(xp);
        float4 xb = *(const float4*)(xp + 4);
        float4 wa = *(const float4*)(wp);
        float4 wb = *(const float4*)(wp + 4);
#pragma unroll 4
        for (int k = 0; k < 64; k++) {
            float4 xan, xbn, wan, wbn;
            if (k < 63) {
                xan = *(const float4*)(xp + (k + 1) * 64);
                xbn = *(const float4*)(xp + (k + 1) * 64 + 4);
                wan = *(const float4*)(wp + (k + 1) * 64);
                wbn = *(const float4*)(wp + (k + 1) * 64 + 4);
            }
            float xv[8] = {xa.x, xa.y, xa.z, xa.w, xb.x, xb.y, xb.z, xb.w};
            float wc[8] = {wa.x, wa.y, wa.z, wa.w, wb.x, wb.y, wb.z, wb.w};
#pragma unroll
            for (int i = 0; i < 8; i++)
#pragma unroll
                for (int j = 0; j < 8; j++)
                    acc[i][j] = fmaf(xv[i], wc[j], acc[i][j]);
            xa = xan; xb = xbn; wa = wan; wb = wbn;
        }

#pragma unroll
        for (int i = 0; i < 8; i++) {
            int row = base + lr * 8 + i;
            if (row < N) {
                if (m == 0) {
                    float* dst = &Q[(size_t)row * 64 + lc * 8];
                    ((float4*)dst)[0] = make_float4(acc[i][0], acc[i][1], acc[i][2], acc[i][3]);
                    ((float4*)dst)[1] = make_float4(acc[i][4], acc[i][5], acc[i][6], acc[i][7]);
                } else {
                    // KV row = 128 bf16 (256 B): [0:64)=K, [64:128)=V; as uint2-pairs
                    unsigned int* dst = &KVb[(size_t)row * 64 + (m - 1) * 32 + lc * 4];
                    uint4 pk;
                    pk.x = pack2bf(acc[i][0], acc[i][1]);
                    pk.y = pack2bf(acc[i][2], acc[i][3]);
                    pk.z = pack2bf(acc[i][4], acc[i][5]);
                    pk.w = pack2bf(acc[i][6], acc[i][7]);
                    *((uint4*)dst) = pk;
                }
            }
        }
    }
}

// ---------------- attention + fused output GEMM ----------------
// One wave per receiver; 8 groups of 8 lanes, each group one edge, each lane
// 8 dims via one 16-B bf16x8 load -> 8 edges per wave-iteration (2x R3) at
// half the gather bytes. 2-deep software pipeline on (csr, K, V) gathers.
// Group dot-reduce: shfl_xor 1/2/4; cross-group combine: shfl_xor 8/16/32.
__global__ __launch_bounds__(256) void k_attn(const float* __restrict__ Q,
                                              const unsigned int* __restrict__ KVb,
                                              const float* __restrict__ x,
                                              const float* __restrict__ Wo,
                                              const int* __restrict__ offs,
                                              const int* __restrict__ csr,
                                              float* __restrict__ out, int N) {
    __shared__ float wos[64 * 64];          // Wo[k][j] at wos[k*64+j]
    __shared__ __align__(16) float osh[4][64];
    int tid = threadIdx.x;
    int wv = tid >> 6;
    int lane = tid & 63;
    int g = lane >> 3;      // group = edge slot (8 per iter)
    int sub = lane & 7;     // 8 dims per lane: [sub*8, sub*8+8)

    for (int i = tid; i < 4096; i += 256) wos[i] = Wo[i];
    __syncthreads();

    int wave_id = blockIdx.x * 4 + wv;
    int nwaves = gridDim.x * 4;

    for (int r = wave_id; r < N; r += nwaves) {
        int start = offs[r];
        int end = offs[r + 1];
        float xres = x[(size_t)r * 64 + lane];
        float4 qa = *((const float4*)&Q[(size_t)r * 64 + sub * 8]);
        float4 qb = *((const float4*)&Q[(size_t)r * 64 + sub * 8 + 4]);
        float q[8] = {qa.x, qa.y, qa.z, qa.w, qb.x, qb.y, qb.z, qb.w};
        float acc[8] = {0.f, 0.f, 0.f, 0.f, 0.f, 0.f, 0.f, 0.f};
        float dpart = 0.f;

        // 2-stage pipeline over 8-edge batches
        int eA = start + g;
        bool vA = eA < end;
        int sA = vA ? csr[eA] : 0;
        uint4 kA = *((const uint4*)&KVb[(size_t)sA * 64 + sub * 4]);
        uint4 uA = *((const uint4*)&KVb[(size_t)sA * 64 + 32 + sub * 4]);
        int eB = start + 8 + g;
        bool vB = eB < end;
        int sB = vB ? csr[eB] : 0;
        uint4 kB = *((const uint4*)&KVb[(size_t)sB * 64 + sub * 4]);
        uint4 uB = *((const uint4*)&KVb[(size_t)sB * 64 + 32 + sub * 4]);

        for (int b = start; b < end; b += 8) {
            int eC = b + 16 + g;
            bool vC = eC < end;
            int sC = vC ? csr[eC] : 0;
            uint4 kC = *((const uint4*)&KVb[(size_t)sC * 64 + sub * 4]);
            uint4 uC = *((const uint4*)&KVb[(size_t)sC * 64 + 32 + sub * 4]);

            // dot: 8 bf16 K dims vs q[8]
            float2 k01 = unpack2bf(kA.x), k23 = unpack2bf(kA.y);
            float2 k45 = unpack2bf(kA.z), k67 = unpack2bf(kA.w);
            float dot = q[0] * k01.x + q[1] * k01.y + q[2] * k23.x + q[3] * k23.y
                      + q[4] * k45.x + q[5] * k45.y + q[6] * k67.x + q[7] * k67.y;
            dot += __shfl_xor(dot, 1);
            dot += __shfl_xor(dot, 2);
            dot += __shfl_xor(dot, 4);
            float w = vA ? __expf(dot * SCALE) : 0.f;

            float2 v01 = unpack2bf(uA.x), v23 = unpack2bf(uA.y);
            float2 v45 = unpack2bf(uA.z), v67 = unpack2bf(uA.w);
            acc[0] = fmaf(w, v01.x, acc[0]);
            acc[1] = fmaf(w, v01.y, acc[1]);
            acc[2] = fmaf(w, v23.x, acc[2]);
            acc[3] = fmaf(w, v23.y, acc[3]);
            acc[4] = fmaf(w, v45.x, acc[4]);
            acc[5] = fmaf(w, v45.y, acc[5]);
            acc[6] = fmaf(w, v67.x, acc[6]);
            acc[7] = fmaf(w, v67.y, acc[7]);
            dpart += w;

            kA = kB; uA = uB; vA = vB;
            kB = kC; uB = uC; vB = vC;
        }

        // combine the 8 groups' partials (group bits = lane bits 3..5)
        dpart += __shfl_xor(dpart, 8); dpart += __shfl_xor(dpart, 16); dpart += __shfl_xor(dpart, 32);
#pragma unroll
        for (int j = 0; j < 8; j++) {
            acc[j] += __shfl_xor(acc[j], 8);
            acc[j] += __shfl_xor(acc[j], 16);
            acc[j] += __shfl_xor(acc[j], 32);
        }

        float inv = (dpart > 0.f) ? (1.0f / dpart) : 0.f;

        if (lane < 8) {
            *((float4*)&osh[wv][sub * 8]) = make_float4(acc[0] * inv, acc[1] * inv,
                                                        acc[2] * inv, acc[3] * inv);
            *((float4*)&osh[wv][sub * 8 + 4]) = make_float4(acc[4] * inv, acc[5] * inv,
                                                            acc[6] * inv, acc[7] * inv);
        }
        asm volatile("s_waitcnt lgkmcnt(0)" ::: "memory");

        float res = xres;
        const float4* o4p = (const float4*)&osh[wv][0];
#pragma unroll
        for (int k4i = 0; k4i < 16; k4i++) {
            float4 ov = o4p[k4i];
            res = fmaf(ov.x, wos[(k4i * 4 + 0) * 64 + lane], res);
            res = fmaf(ov.y, wos[(k4i * 4 + 1) * 64 + lane], res);
            res = fmaf(ov.z, wos[(k4i * 4 + 2) * 64 + lane], res);
            res = fmaf(ov.w, wos[(k4i * 4 + 3) * 64 + lane], res);
        }
        out[(size_t)r * 64 + lane] = res;
        asm volatile("s_waitcnt lgkmcnt(0)" ::: "memory");  // osh reads done before next node
    }
}

// ---------------- launch ----------------

extern "C" void kernel_launch(void* const* d_in, const int* in_sizes, int n_in,
                              void* d_out, int out_size, void* d_ws, size_t ws_size,
                              hipStream_t stream) {
    const float* x  = (const float*)d_in[0];
    const int* edge = (const int*)d_in[1];
    const float* Wq = (const float*)d_in[2];
    const float* Wk = (const float*)d_in[3];
    const float* Wv = (const float*)d_in[4];
    const float* Wo = (const float*)d_in[5];
    float* out = (float*)d_out;

    int N = in_sizes[0] / DIM;
    int E = in_sizes[1] / 2;

    char* p = (char*)d_ws;
    auto carve = [&](size_t bytes) {
        char* r = p;
        p += ((bytes + 255) / 256) * 256;
        return r;
    };
    float*        Q      = (float*)carve((size_t)N * 64 * 4);
    unsigned int* KVb    = (unsigned int*)carve((size_t)N * 64 * 4);  // 128 bf16/row
    int*          deg    = (int*)carve((size_t)N * 4);
    int*          offs   = (int*)carve((size_t)(N + 1) * 4);
    int*          cursor = (int*)carve((size_t)N * 4);
    int*          bsums  = (int*)carve(4096);
    int*          csr    = (int*)carve((size_t)E * 4);
    (void)ws_size; (void)n_in; (void)out_size;

    const int* send = edge;
    const int* recv = edge + E;

    hipMemsetAsync(deg, 0, (size_t)N * 4, stream);
    k_hist<<<(E + 255) / 256, 256, 0, stream>>>(recv, deg, E);
    int NB = (N + 1023) / 1024;
    k_scan1<<<NB, 1024, 0, stream>>>(deg, offs, bsums, N);
    k_scan2<<<1, 1024, 0, stream>>>(bsums, NB);
    k_scan3<<<(N + 255) / 256, 256, 0, stream>>>(deg, bsums, offs, cursor, N, E);
    k_scatter<<<(E + 255) / 256, 256, 0, stream>>>(send, recv, cursor, csr, E);
    int nchunk = (N + 255) / 256;
    k_qkv<<<3 * nchunk, 256, 0, stream>>>(x, Wq, Wk, Wv, Q, KVb, N, nchunk);
    k_attn<<<4096, 256, 0, stream>>>(Q, KVb, x, Wo, offs, csr, out, N);
}